// Round 4
// baseline (193.061 us; speedup 1.0000x reference)
//
#include <hip/hip_runtime.h>

// diff_round(x) = x - sin(2*pi*x)/(2*pi).
// v_sin_f32 takes REVOLUTIONS: __builtin_amdgcn_sinf(x) == sin(2*pi*x),
// so one v_sin + one v_fma per diff_round, zero range reduction.
// All operands stay in ~[0, 1] -> well inside the HW-valid domain.
__device__ __forceinline__ float dround(float x) {
    return __builtin_fmaf(-0.15915494309189535f, __builtin_amdgcn_sinf(x), x);
}
__device__ __forceinline__ float hdr(float x) { return dround(dround(dround(x))); }

// Per-pixel mask value m given the pixel's 4 channels c and the hoisted
// per-area hdr(initial_mask_id) values hb[] and vb[] = 1 - hb[].
__device__ __forceinline__ float mask_m(float4 c, const float* hb, const float* vb) {
    float cc[4] = { c.x, c.y, c.z, c.w };
    float e[4];
#pragma unroll
    for (int k = 0; k < 4; ++k) {
        float ha = hdr(cc[k]);                                     // harder_diff_round(mask ch)
        float t  = __builtin_fmaf(ha, hb[k], (1.0f - ha) * vb[k]); // a*b + (1-a)*(1-b)
        e[k] = hdr(t);                                             // differentiable_eq
    }
    float a = dround(e[0]) * dround(e[1]);   // differentiable_and(c0,c1)
    float b = dround(e[2]) * dround(e[3]);   // differentiable_and(c2,c3)
    return dround(a) * dround(b);            // differentiable_and(a,b)
}

// One wave (64 lanes) per (b,n) area; each lane owns 4 contiguous pixels.
// Block = 256 threads = 4 independent areas; no LDS, no __syncthreads.
__global__ __launch_bounds__(256) void De_conv_areas_kernel(
    const float* __restrict__ img,       // [A,256,1] f32
    const float* __restrict__ mask,      // [A,256,4] f32
    const float* __restrict__ mask_alt,  // [A,256,4] f32
    const float* __restrict__ mask_id,   // [A,4]     f32
    float* __restrict__ out,             // [A,256]   f32  (output 0)
    float* __restrict__ out_alt,         // [A,256]   f32  (output 1)
    int n_areas)
{
    const int lane = threadIdx.x & 63;
    const int wave = blockIdx.x * (blockDim.x >> 6) + (threadIdx.x >> 6);
    if (wave >= n_areas) return;

    // Per-area id (wave-uniform, L1 broadcast): hoist harder_diff_round.
    float4 idv = *(const float4*)(mask_id + (size_t)wave * 4);
    float hb[4], vb[4];
    hb[0] = hdr(idv.x); hb[1] = hdr(idv.y); hb[2] = hdr(idv.z); hb[3] = hdr(idv.w);
#pragma unroll
    for (int k = 0; k < 4; ++k) vb[k] = 1.0f - hb[k];

    const size_t pix = (size_t)wave * 256 + (size_t)lane * 4;

    float4 im = *(const float4*)(img + pix);                 // 16 B/lane, coalesced
    float imv[4] = { im.x, im.y, im.z, im.w };

    // One float4 per pixel = its 4 channels; 64 B/lane per mask, coalesced.
    const float4* mp0 = (const float4*)(mask     + pix * 4);
    const float4* mp1 = (const float4*)(mask_alt + pix * 4);

    float m0[4], m1[4];
    float sm0 = 0.f, si0 = 0.f, sm1 = 0.f, si1 = 0.f;
#pragma unroll
    for (int j = 0; j < 4; ++j) {
        m0[j] = mask_m(mp0[j], hb, vb);
        m1[j] = mask_m(mp1[j], hb, vb);
        sm0 += m0[j]; si0 += m0[j] * imv[j];
        sm1 += m1[j]; si1 += m1[j] * imv[j];
    }

    // Wave-wide butterfly reduction (64 lanes) for num/den of both masks.
#pragma unroll
    for (int off = 32; off; off >>= 1) {
        sm0 += __shfl_xor(sm0, off, 64);
        si0 += __shfl_xor(si0, off, 64);
        sm1 += __shfl_xor(sm1, off, 64);
        si1 += __shfl_xor(si1, off, 64);
    }

    // Guard 0/0: m >= 0 sums, so sm==0 implies every m==0 -> output 0.
    const float mean0 = (sm0 > 0.f) ? (si0 / sm0) : 0.f;
    const float mean1 = (sm1 > 0.f) ? (si1 / sm1) : 0.f;

    float4 o0, o1;
    o0.x = m0[0] * mean0; o0.y = m0[1] * mean0;
    o0.z = m0[2] * mean0; o0.w = m0[3] * mean0;
    o1.x = m1[0] * mean1; o1.y = m1[1] * mean1;
    o1.z = m1[2] * mean1; o1.w = m1[3] * mean1;
    *(float4*)(out     + pix) = o0;                          // 16 B/lane, coalesced
    *(float4*)(out_alt + pix) = o1;
}

extern "C" void kernel_launch(void* const* d_in, const int* in_sizes, int n_in,
                              void* d_out, int out_size, void* d_ws, size_t ws_size,
                              hipStream_t stream) {
    // setup_inputs() order (all float32 per reference):
    // 0: resized_image      [B,N,16,16,1]
    // 1: mask_combined      [B,N,16,16,4]
    // 2: mask_combined_alt  [B,N,16,16,4]
    // 3: initial_mask_id    [B,N,4]
    // 4: mask_new_bi_channel (unused)
    // 5: mask_index          (unused)
    const float* img      = (const float*)d_in[0];
    const float* mask     = (const float*)d_in[1];
    const float* mask_alt = (const float*)d_in[2];
    const float* mask_id  = (const float*)d_in[3];

    // Output = (out_image, out_image_alt) concatenated: out_size = 2 * A * 256
    // elements -> derive area count from the buffer we actually write.
    const int n_areas = out_size / 512;             // B*N = 16384
    float* out     = (float*)d_out;
    float* out_alt = out + (size_t)n_areas * 256;

    const int waves_per_block = 4;                  // 256 threads
    const int blocks = (n_areas + waves_per_block - 1) / waves_per_block;
    De_conv_areas_kernel<<<blocks, 256, 0, stream>>>(
        img, mask, mask_alt, mask_id, out, out_alt, n_areas);
}

// Round 5
// 190.434 us; speedup vs baseline: 1.0138x; 1.0138x over previous
//
#include <hip/hip_runtime.h>

// diff_round(x) = x - sin(2*pi*x)/(2*pi).
// v_sin_f32 takes REVOLUTIONS: __builtin_amdgcn_sinf(x) == sin(2*pi*x),
// so one v_sin + one v_fma per diff_round, zero range reduction.
__device__ __forceinline__ float dround(float x) {
    return __builtin_fmaf(-0.15915494309189535f, __builtin_amdgcn_sinf(x), x);
}
__device__ __forceinline__ float hdr(float x) { return dround(dround(dround(x))); }

// Per-pixel mask value m given the pixel's 4 channels c and the hoisted
// per-area hdr(initial_mask_id) values hb[] and vb[] = 1 - hb[].
__device__ __forceinline__ float mask_m(float4 c, const float* hb, const float* vb) {
    float cc[4] = { c.x, c.y, c.z, c.w };
    float e[4];
#pragma unroll
    for (int k = 0; k < 4; ++k) {
        float ha = hdr(cc[k]);                                     // harder_diff_round(mask ch)
        float t  = __builtin_fmaf(ha, hb[k], (1.0f - ha) * vb[k]); // a*b + (1-a)*(1-b)
        e[k] = hdr(t);                                             // differentiable_eq
    }
    float a = dround(e[0]) * dround(e[1]);   // differentiable_and(c0,c1)
    float b = dround(e[2]) * dround(e[3]);   // differentiable_and(c2,c3)
    return dround(a) * dround(b);            // differentiable_and(a,b)
}

// One wave (64 lanes) per (area, mask-variant): 2x the waves of the per-area
// version -> shorter per-wave latency, more TLP to hide v_sin/VMEM latency.
// Each lane owns 4 contiguous pixels of one mask variant.
// __launch_bounds__(256, 4): target 4 waves/EU (the measured residency),
// VGPR cap ~128 -> scheduler keeps multiple sin->fma chains in flight
// instead of serializing for an occupancy tier it doesn't reach.
__global__ __launch_bounds__(256, 4) void De_conv_areas_kernel(
    const float* __restrict__ img,       // [A,256,1] f32
    const float* __restrict__ mask,      // [A,256,4] f32
    const float* __restrict__ mask_alt,  // [A,256,4] f32
    const float* __restrict__ mask_id,   // [A,4]     f32
    float* __restrict__ out,             // [A,256]   f32  (output 0)
    float* __restrict__ out_alt,         // [A,256]   f32  (output 1)
    int n_areas)
{
    const int lane = threadIdx.x & 63;
    const int w    = blockIdx.x * (blockDim.x >> 6) + (threadIdx.x >> 6);
    const int area  = w >> 1;
    const int which = w & 1;                 // 0 -> mask/out, 1 -> mask_alt/out_alt
    if (area >= n_areas) return;

    const float* msk = which ? mask_alt : mask;   // wave-uniform select
    float*       dst = which ? out_alt  : out;

    // Per-area id (wave-uniform, L1 broadcast): hoist harder_diff_round.
    float4 idv = *(const float4*)(mask_id + (size_t)area * 4);
    float hb[4], vb[4];
    hb[0] = hdr(idv.x); hb[1] = hdr(idv.y); hb[2] = hdr(idv.z); hb[3] = hdr(idv.w);
#pragma unroll
    for (int k = 0; k < 4; ++k) vb[k] = 1.0f - hb[k];

    const size_t pix = (size_t)area * 256 + (size_t)lane * 4;

    float4 im = *(const float4*)(img + pix);                 // 16 B/lane, coalesced
    float imv[4] = { im.x, im.y, im.z, im.w };

    // One float4 per pixel = its 4 channels; 64 B/lane, coalesced.
    const float4* mp = (const float4*)(msk + pix * 4);

    float m[4];
    float sm = 0.f, si = 0.f;
#pragma unroll
    for (int j = 0; j < 4; ++j) {
        m[j] = mask_m(mp[j], hb, vb);
        sm += m[j]; si += m[j] * imv[j];
    }

    // Wave-wide butterfly reduction (64 lanes) for num/den.
#pragma unroll
    for (int off = 32; off; off >>= 1) {
        sm += __shfl_xor(sm, off, 64);
        si += __shfl_xor(si, off, 64);
    }

    // Guard 0/0: m >= 0 sums, so sm==0 implies every m==0 -> output 0.
    const float mean = (sm > 0.f) ? (si / sm) : 0.f;

    float4 o;
    o.x = m[0] * mean; o.y = m[1] * mean; o.z = m[2] * mean; o.w = m[3] * mean;
    *(float4*)(dst + pix) = o;                               // 16 B/lane, coalesced
}

extern "C" void kernel_launch(void* const* d_in, const int* in_sizes, int n_in,
                              void* d_out, int out_size, void* d_ws, size_t ws_size,
                              hipStream_t stream) {
    // setup_inputs() order (all float32 per reference):
    // 0: resized_image      [B,N,16,16,1]
    // 1: mask_combined      [B,N,16,16,4]
    // 2: mask_combined_alt  [B,N,16,16,4]
    // 3: initial_mask_id    [B,N,4]
    // 4: mask_new_bi_channel (unused)
    // 5: mask_index          (unused)
    const float* img      = (const float*)d_in[0];
    const float* mask     = (const float*)d_in[1];
    const float* mask_alt = (const float*)d_in[2];
    const float* mask_id  = (const float*)d_in[3];

    const int n_areas = out_size / 512;             // B*N = 16384
    float* out     = (float*)d_out;
    float* out_alt = out + (size_t)n_areas * 256;

    // 2 waves per area (one per mask variant), 4 waves per 256-thread block.
    const int n_waves = n_areas * 2;
    const int waves_per_block = 4;
    const int blocks = (n_waves + waves_per_block - 1) / waves_per_block;
    De_conv_areas_kernel<<<blocks, 256, 0, stream>>>(
        img, mask, mask_alt, mask_id, out, out_alt, n_areas);
}